// Round 4
// baseline (150.144 us; speedup 1.0000x reference)
//
#include <hip/hip_runtime.h>
#include <math.h>

#define BB 8
#define NN 1000
#define CC 81
#define NC 80                     // foreground classes
#define IMG_W_M1 1332.0f
#define IMG_H_M1 799.0f
#define SCORE_THRESH 0.05f
#define NMS_THRESH 0.5f
#define DETS 100
#define DW_CLIP 4.135166556742356f  // log(1000/16) rounded to f32
#define NBINS 4096
#define SELCAP 2048
#define CCAP 1000                 // per-(img,cls) candidate cap == NN: cannot overflow

// ws layout (bytes):
//   [0,        2560000)  pT       f32[8][80][1000]  transposed fg probabilities
//   [2560000,  5120000)  keepgrid f32[8][80][1000]  kept score or 0 (== reference sc array)

__global__ __launch_bounds__(64) void prob_t(
    const float* __restrict__ logits, float* __restrict__ pT) {
#pragma clang fp contract(off)
  int r = blockIdx.x * 64 + threadIdx.x;
  if (r >= BB * NN) return;
  const float* l = logits + (size_t)r * CC;
  float m = l[0];
  for (int c = 1; c < CC; ++c) m = fmaxf(m, l[c]);
  float s = 0.0f;
  for (int c = 0; c < CC; ++c) s += expf(l[c] - m);
  int img = r / NN;
  int row = r - img * NN;
  float* base = pT + (size_t)img * NC * NN + row;
  for (int c = 1; c < CC; ++c)           // coalesced: lanes = adjacent rows
    base[(size_t)(c - 1) * NN] = expf(l[c] - m) / s;
}

__global__ __launch_bounds__(64) void per_class_nms(
    const float* __restrict__ pT, const float* __restrict__ reg,
    const float* __restrict__ props, float* __restrict__ keepgrid) {
#pragma clang fp contract(off)
  __shared__ float s_score[CCAP];
  __shared__ int   s_idx[CCAP];
  __shared__ float s_sscore[CCAP];
  __shared__ int   s_sidx[CCAP];
  __shared__ float s_box[CCAP * 4];
  __shared__ unsigned char s_keep[CCAP];
  __shared__ float s_out[NN];
  __shared__ int s_cnt;

  const int img = blockIdx.x / NC;
  const int cm1 = blockIdx.x % NC;
  const int cls = cm1 + 1;
  const int t = threadIdx.x;

  if (t == 0) s_cnt = 0;
  __syncthreads();

  // Phase 1: coalesced prob read, threshold, compact; zero the output row.
  const float* pcell = pT + ((size_t)img * NC + cm1) * NN;
  for (int r = t; r < NN; r += 64) {
    s_out[r] = 0.0f;
    float p = pcell[r];
    if (p > SCORE_THRESH) {
      int pos = atomicAdd(&s_cnt, 1);
      s_score[pos] = p;
      s_idx[pos] = r;
    }
  }
  __syncthreads();
  const int n = s_cnt;

  // Phase 2: rank sort by (score desc, row asc) == stable argsort(-scores)
  for (int i = t; i < n; i += 64) {
    float si = s_score[i];
    int   ii = s_idx[i];
    int rank = 0;
    for (int j = 0; j < n; ++j) {
      float sj = s_score[j];
      rank += (int)((sj > si) | ((sj == si) & (s_idx[j] < ii)));
    }
    s_sscore[rank] = si;
    s_sidx[rank] = ii;
  }
  __syncthreads();

  // Phase 3: decode + clip (BoxCoder.decode, TO_REMOVE=1); keep lane-locals for
  // the n<=64 fast path (loop runs exactly once per lane then).
  float dbx1 = 0.f, dby1 = 0.f, dbx2 = 0.f, dby2 = 0.f;
  for (int i = t; i < n; i += 64) {
    int r = s_sidx[i];
    int row = img * NN + r;
    float x1 = props[row * 4 + 0], y1 = props[row * 4 + 1];
    float x2 = props[row * 4 + 2], y2 = props[row * 4 + 3];
    float w = x2 - x1 + 1.0f, h = y2 - y1 + 1.0f;
    float cx = x1 + 0.5f * w,  cy = y1 + 0.5f * h;
    const float* rg = reg + (size_t)row * (CC * 4) + cls * 4;
    float dx = rg[0] / 10.0f, dy = rg[1] / 10.0f;
    float dw = fminf(rg[2] / 5.0f, DW_CLIP);
    float dh = fminf(rg[3] / 5.0f, DW_CLIP);
    float pcx = dx * w + cx, pcy = dy * h + cy;
    float pw = expf(dw) * w, ph = expf(dh) * h;
    float bx1 = pcx - 0.5f * pw;
    float by1 = pcy - 0.5f * ph;
    float bx2 = pcx + 0.5f * pw - 1.0f;
    float by2 = pcy + 0.5f * ph - 1.0f;
    bx1 = fminf(fmaxf(bx1, 0.0f), IMG_W_M1);
    bx2 = fminf(fmaxf(bx2, 0.0f), IMG_W_M1);
    by1 = fminf(fmaxf(by1, 0.0f), IMG_H_M1);
    by2 = fminf(fmaxf(by2, 0.0f), IMG_H_M1);
    s_box[i * 4 + 0] = bx1;
    s_box[i * 4 + 1] = by1;
    s_box[i * 4 + 2] = bx2;
    s_box[i * 4 + 3] = by2;
    s_keep[i] = 1;
    dbx1 = bx1; dby1 = by1; dbx2 = bx2; dby2 = by2;
  }
  __syncthreads();

  // Phase 4: greedy NMS.
  if (n <= 64) {
    // Wave-ballot path: lane t owns sorted candidate t. No barriers.
    bool own = t < n;
    float areaSelf = (dbx2 - dbx1) * (dby2 - dby1);
    unsigned long long rem = __ballot(own);
    unsigned long long kept = 0ull;
    while (rem) {
      int i = __builtin_ctzll(rem);            // highest-score remaining
      kept |= 1ull << i;
      rem &= ~(1ull << i);
      float bx1 = __shfl(dbx1, i), by1 = __shfl(dby1, i);
      float bx2 = __shfl(dbx2, i), by2 = __shfl(dby2, i);
      float areaB = (bx2 - bx1) * (by2 - by1);
      float wx = fmaxf(fminf(dbx2, bx2) - fmaxf(dbx1, bx1), 0.0f);
      float wy = fmaxf(fminf(dby2, by2) - fmaxf(dby1, by1), 0.0f);
      float inter = wx * wy;
      float iou = inter / ((areaSelf + areaB) - inter + 1e-9f);  // A+B commutative: bit-equal to ref
      unsigned long long sup = __ballot(iou > NMS_THRESH);
      rem &= ~sup;
    }
    if (own && ((kept >> t) & 1ull)) s_out[s_sidx[t]] = s_sscore[t];
  } else {
    // Generic fallback (n>64): barriered LDS loop, identical semantics.
    for (int i = 0; i < n; ++i) {
      if (s_keep[i]) {
        float ax1 = s_box[i * 4 + 0], ay1 = s_box[i * 4 + 1];
        float ax2 = s_box[i * 4 + 2], ay2 = s_box[i * 4 + 3];
        float areaA = (ax2 - ax1) * (ay2 - ay1);
        for (int j = i + 1 + t; j < n; j += 64) {
          if (!s_keep[j]) continue;
          float bx1 = s_box[j * 4 + 0], by1 = s_box[j * 4 + 1];
          float bx2 = s_box[j * 4 + 2], by2 = s_box[j * 4 + 3];
          float areaB = (bx2 - bx1) * (by2 - by1);
          float wx = fmaxf(fminf(ax2, bx2) - fmaxf(ax1, bx1), 0.0f);
          float wy = fmaxf(fminf(ay2, by2) - fmaxf(ay1, by1), 0.0f);
          float inter = wx * wy;
          float iou = inter / ((areaA + areaB) - inter + 1e-9f);
          if (iou > NMS_THRESH) s_keep[j] = 0;
        }
      }
      __syncthreads();
    }
    for (int i = t; i < n; i += 64)
      if (s_keep[i]) s_out[s_sidx[i]] = s_sscore[i];
  }
  __syncthreads();

  // Phase 5: coalesced dense store (== reference's where(keep, scores, 0))
  float* kcell = keepgrid + ((size_t)img * NC + cm1) * NN;
  for (int r = t; r < NN; r += 64) kcell[r] = s_out[r];
}

#define TK_THREADS 1024

__global__ __launch_bounds__(TK_THREADS) void topk_out(
    const float* __restrict__ keepgrid, const float* __restrict__ reg,
    const float* __restrict__ props, float* __restrict__ dets_out,
    float* __restrict__ labels_out) {
#pragma clang fp contract(off)
  __shared__ unsigned hist[NBINS];
  __shared__ float s_ssc[SELCAP];
  __shared__ int   s_sfl[SELCAP];
  __shared__ int s_m, s_cut, s_P;

  const int img = blockIdx.x;
  const int t = threadIdx.x;
  const int TOT = NC * NN;                       // 80000
  const float* grid = keepgrid + (size_t)img * TOT;
  const float4* g4 = (const float4*)grid;

  if (t == 0) { s_m = 0; s_cut = NBINS; s_P = 0; }
  for (int b = t; b < NBINS; b += TK_THREADS) hist[b] = 0u;
  __syncthreads();

  // Histogram of positive scores only (zeros would serialize on bin 0's bank).
  for (int i = t; i < TOT / 4; i += TK_THREADS) {
    float4 v = g4[i];
    float vv[4] = {v.x, v.y, v.z, v.w};
    for (int c = 0; c < 4; ++c) {
      float sc = vv[c];
      if (sc > 0.0f) {
        int bin = (int)(sc * (float)NBINS);
        if (bin > NBINS - 1) bin = NBINS - 1;
        atomicAdd(&hist[bin], 1u);
      }
    }
  }
  __syncthreads();

  // Wave 0: suffix scan -> total positives P and cutoff bin.
  if (t < 64) {
    unsigned s = 0;
    for (int b = 0; b < 64; ++b) s += hist[t * 64 + b];
    unsigned suf = s;
    for (int d = 1; d < 64; d <<= 1) {
      unsigned o = __shfl_down(suf, d);
      if (t + d < 64) suf += o;
    }
    unsigned total = __shfl(suf, 0);
    if (t == 0) s_P = (int)total;
    int K = (total < (unsigned)DETS) ? (int)total : DETS;
    if (K > 0) {
      unsigned long long m1 = __ballot(suf >= (unsigned)K);
      int S = 63 - __builtin_clzll(m1);
      unsigned tail = 0;
      if (S < 63) tail = __shfl(suf, S + 1);
      unsigned suf2 = hist[S * 64 + t];
      for (int d = 1; d < 64; d <<= 1) {
        unsigned o = __shfl_down(suf2, d);
        if (t + d < 64) suf2 += o;
      }
      unsigned long long m2 = __ballot((suf2 + tail) >= (unsigned)K);
      int Ls = 63 - __builtin_clzll(m2);
      if (t == 0) s_cut = S * 64 + Ls;
    }
  }
  __syncthreads();
  const int P = s_P;
  const int K = (P < DETS) ? P : DETS;
  const int cut = s_cut;

  // Prefill ranks >= K (reference: topv==0 -> box 0, score 0, label -1).
  for (int k = t; k < DETS; k += TK_THREADS) {
    if (k >= K) {
      float* d = dets_out + (size_t)(img * DETS + k) * 5;
      d[0] = 0.0f; d[1] = 0.0f; d[2] = 0.0f; d[3] = 0.0f; d[4] = 0.0f;
      labels_out[img * DETS + k] = -1.0f;
    }
  }

  // Select bin >= cut. floor(sc*4096) monotone & *4096 exact => excluded
  // scores strictly smaller than any selected => in-set rank == global rank.
  for (int i = t; i < TOT / 4; i += TK_THREADS) {
    float4 v = g4[i];
    float vv[4] = {v.x, v.y, v.z, v.w};
    for (int c = 0; c < 4; ++c) {
      float sc = vv[c];
      if (sc > 0.0f) {
        int bin = (int)(sc * (float)NBINS);
        if (bin > NBINS - 1) bin = NBINS - 1;
        if (bin >= cut) {
          int p = atomicAdd(&s_m, 1);
          if (p < SELCAP) { s_ssc[p] = sc; s_sfl[p] = 4 * i + c; }
        }
      }
    }
  }
  __syncthreads();
  const int m = s_m;

  if (m <= SELCAP) {
    for (int i = t; i < m; i += TK_THREADS) {
      float si = s_ssc[i];
      int   fi = s_sfl[i];
      int rank = 0;
      for (int j = 0; j < m; ++j) {
        float sj = s_ssc[j];
        rank += (int)((sj > si) | ((sj == si) & (s_sfl[j] < fi)));
      }
      if (rank < DETS) {
        // Re-decode box for this (cls,row): bit-identical to reference formula.
        int cm1 = fi / NN;
        int r = fi - cm1 * NN;
        int row = img * NN + r;
        float x1 = props[row * 4 + 0], y1 = props[row * 4 + 1];
        float x2 = props[row * 4 + 2], y2 = props[row * 4 + 3];
        float w = x2 - x1 + 1.0f, h = y2 - y1 + 1.0f;
        float cx = x1 + 0.5f * w,  cy = y1 + 0.5f * h;
        const float* rg = reg + (size_t)row * (CC * 4) + (cm1 + 1) * 4;
        float dx = rg[0] / 10.0f, dy = rg[1] / 10.0f;
        float dw = fminf(rg[2] / 5.0f, DW_CLIP);
        float dh = fminf(rg[3] / 5.0f, DW_CLIP);
        float pcx = dx * w + cx, pcy = dy * h + cy;
        float pw = expf(dw) * w, ph = expf(dh) * h;
        float bx1 = fminf(fmaxf(pcx - 0.5f * pw, 0.0f), IMG_W_M1);
        float by1 = fminf(fmaxf(pcy - 0.5f * ph, 0.0f), IMG_H_M1);
        float bx2 = fminf(fmaxf(pcx + 0.5f * pw - 1.0f, 0.0f), IMG_W_M1);
        float by2 = fminf(fmaxf(pcy + 0.5f * ph - 1.0f, 0.0f), IMG_H_M1);
        float* d = dets_out + (size_t)(img * DETS + rank) * 5;
        d[0] = bx1; d[1] = by1; d[2] = bx2; d[3] = by2; d[4] = si;
        labels_out[img * DETS + rank] = (float)(cm1 + 1);
      }
    }
  } else {
    // Never-taken (mass-tie) fallback: rank every positive vs the full grid.
    for (int i = t; i < TOT; i += TK_THREADS) {
      float si = grid[i];
      if (si > 0.0f) {
        int rank = 0;
        for (int j = 0; j < TOT; ++j) {
          float sj = grid[j];
          rank += (int)((sj > si) | ((sj == si) & (j < i)));
        }
        if (rank < DETS) {
          int cm1 = i / NN;
          int r = i - cm1 * NN;
          int row = img * NN + r;
          float x1 = props[row * 4 + 0], y1 = props[row * 4 + 1];
          float x2 = props[row * 4 + 2], y2 = props[row * 4 + 3];
          float w = x2 - x1 + 1.0f, h = y2 - y1 + 1.0f;
          float cx = x1 + 0.5f * w,  cy = y1 + 0.5f * h;
          const float* rg = reg + (size_t)row * (CC * 4) + (cm1 + 1) * 4;
          float dx = rg[0] / 10.0f, dy = rg[1] / 10.0f;
          float dw = fminf(rg[2] / 5.0f, DW_CLIP);
          float dh = fminf(rg[3] / 5.0f, DW_CLIP);
          float pcx = dx * w + cx, pcy = dy * h + cy;
          float pw = expf(dw) * w, ph = expf(dh) * h;
          float bx1 = fminf(fmaxf(pcx - 0.5f * pw, 0.0f), IMG_W_M1);
          float by1 = fminf(fmaxf(pcy - 0.5f * ph, 0.0f), IMG_H_M1);
          float bx2 = fminf(fmaxf(pcx + 0.5f * pw - 1.0f, 0.0f), IMG_W_M1);
          float by2 = fminf(fmaxf(pcy + 0.5f * ph - 1.0f, 0.0f), IMG_H_M1);
          float* d = dets_out + (size_t)(img * DETS + rank) * 5;
          d[0] = bx1; d[1] = by1; d[2] = bx2; d[3] = by2; d[4] = si;
          labels_out[img * DETS + rank] = (float)(cm1 + 1);
        }
      }
    }
  }
}

extern "C" void kernel_launch(void* const* d_in, const int* in_sizes, int n_in,
                              void* d_out, int out_size, void* d_ws, size_t ws_size,
                              hipStream_t stream) {
  const float* logits = (const float*)d_in[0];   // [8000, 81]
  const float* reg    = (const float*)d_in[1];   // [8000, 324]
  const float* props  = (const float*)d_in[2];   // [8000, 4]
  // d_in[3] = features, unused (OUTPUT_FEATURE=False)

  float* out = (float*)d_out;                    // dets [8,100,5] then labels [8,100]
  char* ws = (char*)d_ws;
  float* pT       = (float*)(ws);
  float* keepgrid = (float*)(ws + (size_t)BB * NC * NN * 4);

  prob_t<<<(BB * NN + 63) / 64, 64, 0, stream>>>(logits, pT);
  per_class_nms<<<BB * NC, 64, 0, stream>>>(pT, reg, props, keepgrid);
  topk_out<<<BB, TK_THREADS, 0, stream>>>(keepgrid, reg, props,
                                          out, out + BB * DETS * 5);
}

// Round 5
// 129.267 us; speedup vs baseline: 1.1615x; 1.1615x over previous
//
#include <hip/hip_runtime.h>
#include <math.h>

#define BB 8
#define NN 1000
#define CC 81
#define NC 80                     // foreground classes
#define IMG_W_M1 1332.0f
#define IMG_H_M1 799.0f
#define SCORE_THRESH 0.05f
#define NMS_THRESH 0.5f
#define DETS 100
#define DW_CLIP 4.135166556742356f  // log(1000/16) rounded to f32
#define NBINS 4096
#define SELCAP 2048
#define CAP 8192                  // per-image survivor capacity
#define RPB 64                    // rows per block in prob_t

// ws layout (bytes):
//   [0,        2560000)  pT       f32[8][80][1000] transposed fg probabilities
//   [2560000,  2560032)  counters u32[8]
//   [2560064,  3084352)  cand     float2[8][CAP] = {score, bitcast(flatidx)}

__global__ __launch_bounds__(64) void prob_t(
    const float* __restrict__ logits, float* __restrict__ pT,
    unsigned* __restrict__ counters) {
#pragma clang fp contract(off)
  __shared__ float s_l[RPB * CC];          // 20736 B
  const int b = blockIdx.x;
  const int t = threadIdx.x;
  if (b == 0 && t < BB) counters[t] = 0u;

  // Coalesced staging: this block's 64 rows are 5184 contiguous floats.
  const float4* src = (const float4*)(logits + (size_t)b * RPB * CC);
  float4* dst = (float4*)s_l;
  for (int i = t; i < RPB * CC / 4; i += 64) dst[i] = src[i];
  __syncthreads();

  const int rg = b * RPB + t;              // 125*64 == 8000 exactly
  const int img = rg / NN;
  const int row = rg - img * NN;
  float* l = s_l + t * CC;                 // stride 81: 2 lanes/bank -> free

  float m = l[0];
  for (int c = 1; c < CC; ++c) m = fmaxf(m, l[c]);
  float s = 0.0f;
  for (int c = 0; c < CC; ++c) {
    float e = expf(l[c] - m);
    s += e;
    l[c] = e;                              // own row only: no race
  }
  float* base = pT + (size_t)img * NC * NN + row;
  for (int c = 1; c < CC; ++c)             // lanes = adjacent rows: coalesced
    base[(size_t)(c - 1) * NN] = l[c] / s; // identical op order to reference
}

__global__ __launch_bounds__(256) void per_class_nms(
    const float* __restrict__ pT, const float* __restrict__ reg,
    const float* __restrict__ props, unsigned* __restrict__ counters,
    float2* __restrict__ cand) {
#pragma clang fp contract(off)
  __shared__ float s_score[NN];
  __shared__ int   s_idx[NN];
  __shared__ float s_sscore[NN];
  __shared__ int   s_sidx[NN];
  __shared__ float s_box[NN * 4];
  __shared__ unsigned char s_keep[NN];
  __shared__ int s_cnt;
  __shared__ unsigned s_base;

  const int img = blockIdx.x / NC;
  const int cm1 = blockIdx.x % NC;
  const int cls = cm1 + 1;
  const int t = threadIdx.x;

  if (t == 0) s_cnt = 0;
  __syncthreads();

  // Phase 1: coalesced prob read, threshold, compact.
  const float* pcell = pT + ((size_t)img * NC + cm1) * NN;
  for (int r = t; r < NN; r += 256) {
    float p = pcell[r];
    if (p > SCORE_THRESH) {
      int pos = atomicAdd(&s_cnt, 1);
      s_score[pos] = p;
      s_idx[pos] = r;
    }
  }
  __syncthreads();
  const int n = s_cnt;

  // Phase 2: rank sort by (score desc, row asc) == stable argsort(-scores)
  for (int i = t; i < n; i += 256) {
    float si = s_score[i];
    int   ii = s_idx[i];
    int rank = 0;
    for (int j = 0; j < n; ++j) {
      float sj = s_score[j];
      rank += (int)((sj > si) | ((sj == si) & (s_idx[j] < ii)));
    }
    s_sscore[rank] = si;
    s_sidx[rank] = ii;
  }
  __syncthreads();

  // Phase 3: decode + clip (BoxCoder.decode, TO_REMOVE=1)
  for (int i = t; i < n; i += 256) {
    int r = s_sidx[i];
    int row = img * NN + r;
    float x1 = props[row * 4 + 0], y1 = props[row * 4 + 1];
    float x2 = props[row * 4 + 2], y2 = props[row * 4 + 3];
    float w = x2 - x1 + 1.0f, h = y2 - y1 + 1.0f;
    float cx = x1 + 0.5f * w,  cy = y1 + 0.5f * h;
    const float* rg = reg + (size_t)row * (CC * 4) + cls * 4;
    float dx = rg[0] / 10.0f, dy = rg[1] / 10.0f;
    float dw = fminf(rg[2] / 5.0f, DW_CLIP);
    float dh = fminf(rg[3] / 5.0f, DW_CLIP);
    float pcx = dx * w + cx, pcy = dy * h + cy;
    float pw = expf(dw) * w, ph = expf(dh) * h;
    float bx1 = fminf(fmaxf(pcx - 0.5f * pw, 0.0f), IMG_W_M1);
    float by1 = fminf(fmaxf(pcy - 0.5f * ph, 0.0f), IMG_H_M1);
    float bx2 = fminf(fmaxf(pcx + 0.5f * pw - 1.0f, 0.0f), IMG_W_M1);
    float by2 = fminf(fmaxf(pcy + 0.5f * ph - 1.0f, 0.0f), IMG_H_M1);
    s_box[i * 4 + 0] = bx1;
    s_box[i * 4 + 1] = by1;
    s_box[i * 4 + 2] = bx2;
    s_box[i * 4 + 3] = by2;
    s_keep[i] = 1;
  }
  __syncthreads();

  // Phase 4+5: greedy NMS + emit {score, flatidx} to per-image compact list.
  if (n <= 64) {
    // Single-wave ballot path: no barriers, lane i owns sorted candidate i.
    if (t < 64) {
      bool own = t < n;
      float bx1 = 0.f, by1 = 0.f, bx2 = 0.f, by2 = 0.f;
      if (own) {
        bx1 = s_box[t * 4 + 0]; by1 = s_box[t * 4 + 1];
        bx2 = s_box[t * 4 + 2]; by2 = s_box[t * 4 + 3];
      }
      float areaSelf = (bx2 - bx1) * (by2 - by1);
      unsigned long long rem = __ballot(own);
      unsigned long long kept = 0ull;
      while (rem) {
        int i = __builtin_ctzll(rem);          // highest-score remaining
        kept |= 1ull << i;
        rem &= ~(1ull << i);
        float cx1 = __shfl(bx1, i), cy1 = __shfl(by1, i);
        float cx2 = __shfl(bx2, i), cy2 = __shfl(by2, i);
        float areaB = (cx2 - cx1) * (cy2 - cy1);
        float wx = fmaxf(fminf(bx2, cx2) - fmaxf(bx1, cx1), 0.0f);
        float wy = fmaxf(fminf(by2, cy2) - fmaxf(by1, cy1), 0.0f);
        float inter = wx * wy;
        float iou = inter / ((areaSelf + areaB) - inter + 1e-9f); // commutes: bit-eq to ref
        rem &= ~__ballot(iou > NMS_THRESH);
      }
      int tot = __popcll(kept);
      unsigned base = 0u;
      if (t == 0 && tot > 0) base = atomicAdd(&counters[img], (unsigned)tot);
      base = __shfl(base, 0);
      if (own && ((kept >> t) & 1ull)) {
        unsigned pos = base + (unsigned)__popcll(kept & ((1ull << t) - 1ull));
        if (pos < CAP) {
          float2 v;
          v.x = s_sscore[t];
          v.y = __int_as_float(cm1 * NN + s_sidx[t]);
          cand[(size_t)img * CAP + pos] = v;
        }
      }
    }
  } else {
    // Generic fallback (n>64): barriered LDS loop, identical semantics.
    for (int i = 0; i < n; ++i) {
      if (s_keep[i]) {
        float ax1 = s_box[i * 4 + 0], ay1 = s_box[i * 4 + 1];
        float ax2 = s_box[i * 4 + 2], ay2 = s_box[i * 4 + 3];
        float areaA = (ax2 - ax1) * (ay2 - ay1);
        for (int j = i + 1 + t; j < n; j += 256) {
          if (!s_keep[j]) continue;
          float bx1 = s_box[j * 4 + 0], by1 = s_box[j * 4 + 1];
          float bx2 = s_box[j * 4 + 2], by2 = s_box[j * 4 + 3];
          float areaB = (bx2 - bx1) * (by2 - by1);
          float wx = fmaxf(fminf(ax2, bx2) - fmaxf(ax1, bx1), 0.0f);
          float wy = fmaxf(fminf(ay2, by2) - fmaxf(ay1, by1), 0.0f);
          float inter = wx * wy;
          float iou = inter / ((areaA + areaB) - inter + 1e-9f);
          if (iou > NMS_THRESH) s_keep[j] = 0;
        }
      }
      __syncthreads();
    }
    if (t == 0) {
      int tot = 0;
      for (int j = 0; j < n; ++j) tot += s_keep[j];
      s_base = (tot > 0) ? atomicAdd(&counters[img], (unsigned)tot) : 0u;
    }
    __syncthreads();
    for (int i = t; i < n; i += 256) {
      if (s_keep[i]) {
        int pos = 0;
        for (int j = 0; j < i; ++j) pos += (int)s_keep[j];
        unsigned gpos = s_base + (unsigned)pos;
        if (gpos < CAP) {
          float2 v;
          v.x = s_sscore[i];
          v.y = __int_as_float(cm1 * NN + s_sidx[i]);
          cand[(size_t)img * CAP + gpos] = v;
        }
      }
    }
  }
}

__global__ __launch_bounds__(256) void topk_out(
    const unsigned* __restrict__ counters, const float2* __restrict__ cand,
    const float* __restrict__ reg, const float* __restrict__ props,
    float* __restrict__ dets_out, float* __restrict__ labels_out) {
#pragma clang fp contract(off)
  __shared__ unsigned hist[NBINS];
  __shared__ float s_ssc[SELCAP];
  __shared__ int   s_sfl[SELCAP];
  __shared__ int s_m, s_cut;

  const int img = blockIdx.x;
  const int t = threadIdx.x;
  int n = (int)counters[img];
  if (n > CAP) n = CAP;
  const int K = (n < DETS) ? n : DETS;     // all survivors have score > 0.05 > 0
  const float2* cb = cand + (size_t)img * CAP;

  if (t == 0) { s_m = 0; s_cut = NBINS; }
  for (int b = t; b < NBINS; b += 256) hist[b] = 0u;
  __syncthreads();

  // Histogram. bin = floor(sc*4096) monotone in sc => {bin>=cut} upward-closed.
  for (int i = t; i < n; i += 256) {
    float sc = cb[i].x;
    int bin = (int)(sc * (float)NBINS);
    if (bin > NBINS - 1) bin = NBINS - 1;
    atomicAdd(&hist[bin], 1u);
  }
  __syncthreads();

  // Wave 0: suffix scan -> largest cutoff bin with count(bin>=cut) >= K.
  if (t < 64 && K > 0) {
    unsigned s = 0;
    for (int b = 0; b < 64; ++b) s += hist[t * 64 + b];
    unsigned suf = s;
    for (int d = 1; d < 64; d <<= 1) {
      unsigned o = __shfl_down(suf, d);
      if (t + d < 64) suf += o;
    }
    unsigned long long m1 = __ballot(suf >= (unsigned)K);
    int S = 63 - __builtin_clzll(m1);
    unsigned tail = 0;
    if (S < 63) tail = __shfl(suf, S + 1);
    unsigned suf2 = hist[S * 64 + t];
    for (int d = 1; d < 64; d <<= 1) {
      unsigned o = __shfl_down(suf2, d);
      if (t + d < 64) suf2 += o;
    }
    unsigned long long m2 = __ballot((suf2 + tail) >= (unsigned)K);
    int Ls = 63 - __builtin_clzll(m2);
    if (t == 0) s_cut = S * 64 + Ls;
  }
  __syncthreads();
  const int cut = s_cut;

  // Prefill ranks >= K (reference: topv==0 -> box 0, score 0, label -1).
  for (int k = t; k < DETS; k += 256) {
    if (k >= K) {
      float* d = dets_out + (size_t)(img * DETS + k) * 5;
      d[0] = 0.0f; d[1] = 0.0f; d[2] = 0.0f; d[3] = 0.0f; d[4] = 0.0f;
      labels_out[img * DETS + k] = -1.0f;
    }
  }

  // Select bin >= cut (excluded => strictly smaller score => in-set rank ==
  // global rank for every selected item).
  for (int i = t; i < n; i += 256) {
    float sc = cb[i].x;
    int bin = (int)(sc * (float)NBINS);
    if (bin > NBINS - 1) bin = NBINS - 1;
    if (bin >= cut) {
      int p = atomicAdd(&s_m, 1);
      if (p < SELCAP) {
        s_ssc[p] = sc;
        s_sfl[p] = __float_as_int(cb[i].y);
      }
    }
  }
  __syncthreads();
  const int m = s_m;

  if (m <= SELCAP) {
    for (int i = t; i < m; i += 256) {
      float si = s_ssc[i];
      int   fi = s_sfl[i];
      int rank = 0;
      for (int j = 0; j < m; ++j) {
        float sj = s_ssc[j];
        rank += (int)((sj > si) | ((sj == si) & (s_sfl[j] < fi)));
      }
      if (rank < DETS) {
        int cm1 = fi / NN;
        int r = fi - cm1 * NN;
        int row = img * NN + r;
        float x1 = props[row * 4 + 0], y1 = props[row * 4 + 1];
        float x2 = props[row * 4 + 2], y2 = props[row * 4 + 3];
        float w = x2 - x1 + 1.0f, h = y2 - y1 + 1.0f;
        float cx = x1 + 0.5f * w,  cy = y1 + 0.5f * h;
        const float* rg = reg + (size_t)row * (CC * 4) + (cm1 + 1) * 4;
        float dx = rg[0] / 10.0f, dy = rg[1] / 10.0f;
        float dw = fminf(rg[2] / 5.0f, DW_CLIP);
        float dh = fminf(rg[3] / 5.0f, DW_CLIP);
        float pcx = dx * w + cx, pcy = dy * h + cy;
        float pw = expf(dw) * w, ph = expf(dh) * h;
        float bx1 = fminf(fmaxf(pcx - 0.5f * pw, 0.0f), IMG_W_M1);
        float by1 = fminf(fmaxf(pcy - 0.5f * ph, 0.0f), IMG_H_M1);
        float bx2 = fminf(fmaxf(pcx + 0.5f * pw - 1.0f, 0.0f), IMG_W_M1);
        float by2 = fminf(fmaxf(pcy + 0.5f * ph - 1.0f, 0.0f), IMG_H_M1);
        float* d = dets_out + (size_t)(img * DETS + rank) * 5;
        d[0] = bx1; d[1] = by1; d[2] = bx2; d[3] = by2; d[4] = si;
        labels_out[img * DETS + rank] = (float)(cm1 + 1);
      }
    }
  } else {
    // Never-taken (mass-tie) fallback: exact O(n^2) rank via global reads.
    for (int i = t; i < n; i += 256) {
      float si = cb[i].x;
      int   fi = __float_as_int(cb[i].y);
      int rank = 0;
      for (int j = 0; j < n; ++j) {
        float sj = cb[j].x;
        int   fj = __float_as_int(cb[j].y);
        rank += (int)((sj > si) | ((sj == si) & (fj < fi)));
      }
      if (rank < DETS) {
        int cm1 = fi / NN;
        int r = fi - cm1 * NN;
        int row = img * NN + r;
        float x1 = props[row * 4 + 0], y1 = props[row * 4 + 1];
        float x2 = props[row * 4 + 2], y2 = props[row * 4 + 3];
        float w = x2 - x1 + 1.0f, h = y2 - y1 + 1.0f;
        float cx = x1 + 0.5f * w,  cy = y1 + 0.5f * h;
        const float* rg = reg + (size_t)row * (CC * 4) + (cm1 + 1) * 4;
        float dx = rg[0] / 10.0f, dy = rg[1] / 10.0f;
        float dw = fminf(rg[2] / 5.0f, DW_CLIP);
        float dh = fminf(rg[3] / 5.0f, DW_CLIP);
        float pcx = dx * w + cx, pcy = dy * h + cy;
        float pw = expf(dw) * w, ph = expf(dh) * h;
        float bx1 = fminf(fmaxf(pcx - 0.5f * pw, 0.0f), IMG_W_M1);
        float by1 = fminf(fmaxf(pcy - 0.5f * ph, 0.0f), IMG_H_M1);
        float bx2 = fminf(fmaxf(pcx + 0.5f * pw - 1.0f, 0.0f), IMG_W_M1);
        float by2 = fminf(fmaxf(pcy + 0.5f * ph - 1.0f, 0.0f), IMG_H_M1);
        float* d = dets_out + (size_t)(img * DETS + rank) * 5;
        d[0] = bx1; d[1] = by1; d[2] = bx2; d[3] = by2; d[4] = si;
        labels_out[img * DETS + rank] = (float)(cm1 + 1);
      }
    }
  }
}

extern "C" void kernel_launch(void* const* d_in, const int* in_sizes, int n_in,
                              void* d_out, int out_size, void* d_ws, size_t ws_size,
                              hipStream_t stream) {
  const float* logits = (const float*)d_in[0];   // [8000, 81]
  const float* reg    = (const float*)d_in[1];   // [8000, 324]
  const float* props  = (const float*)d_in[2];   // [8000, 4]
  // d_in[3] = features, unused (OUTPUT_FEATURE=False)

  float* out = (float*)d_out;                    // dets [8,100,5] then labels [8,100]
  char* ws = (char*)d_ws;
  float*    pT       = (float*)(ws);
  unsigned* counters = (unsigned*)(ws + 2560000);
  float2*   cand     = (float2*)(ws + 2560064);

  prob_t<<<BB * NN / RPB, 64, 0, stream>>>(logits, pT, counters);
  per_class_nms<<<BB * NC, 256, 0, stream>>>(pT, reg, props, counters, cand);
  topk_out<<<BB, 256, 0, stream>>>(counters, cand, reg, props,
                                   out, out + BB * DETS * 5);
}